// Round 11
// baseline (211.869 us; speedup 1.0000x reference)
//
#include <hip/hip_runtime.h>
#include <hip/hip_fp8.h>

#define NFEAT 256
#define NHID 128
#define NCLASS 40
#define NNODES 50000
#define NEDGES 800000
#define BN_EPS 1e-5f
#define NBK 196          // buckets = dst>>8
#define NBLK2 200        // edge blocks of 4000
#define EPB2 4000
#define NW1 6250         // gemm1 waves: 3125 node-groups x 2 hid-halves
#define GEMM1_BLOCKS 1563

typedef __attribute__((ext_vector_type(4))) float f32x4;
typedef __attribute__((ext_vector_type(8))) short bf16x8;

__device__ inline ushort f2bf(float f) {          // RNE f32 -> bf16
    uint u = __float_as_uint(f);
    u += 0x7FFF + ((u >> 16) & 1);
    return (ushort)(u >> 16);
}
__device__ inline float bflo(uint v) { return __uint_as_float(v << 16); }
__device__ inline float bfhi(uint v) { return __uint_as_float(v & 0xFFFF0000u); }

__device__ inline uint pk_fp8x4(float a0, float a1, float a2, float a3) {
#if __has_builtin(__builtin_amdgcn_cvt_pk_fp8_f32)
    int u = 0;
    u = __builtin_amdgcn_cvt_pk_fp8_f32(a0, a1, u, false);
    u = __builtin_amdgcn_cvt_pk_fp8_f32(a2, a3, u, true);
    return (uint)u;
#else
    __hip_fp8_e4m3 q0(a0), q1(a1), q2(a2), q3(a3);
    return (uint)q0.__x | ((uint)q1.__x << 8) | ((uint)q2.__x << 16) | ((uint)q3.__x << 24);
#endif
}
__device__ inline float fp8lo(uint v) {
#if __has_builtin(__builtin_amdgcn_cvt_f32_fp8)
    return __builtin_amdgcn_cvt_f32_fp8((int)v, 0);
#else
    __hip_fp8_e4m3 q; q.__x = (__hip_fp8_storage_t)(v & 0xFF); return (float)q;
#endif
}
__device__ inline float fp8hi(uint v) {
#if __has_builtin(__builtin_amdgcn_cvt_f32_fp8)
    return __builtin_amdgcn_cvt_f32_fp8((int)v, 1);
#else
    __hip_fp8_e4m3 q; q.__x = (__hip_fp8_storage_t)((v >> 8) & 0xFF); return (float)q;
#endif
}

// ---------------- L1: bucket count (blocks 0-199, atomic-free u8 private hist)
//                     + W0 repack (blocks 200-231) ----------------
__launch_bounds__(128)
__global__ void k_count(const int* __restrict__ ei, int* __restrict__ bcnt,
                        const float* __restrict__ W0, ushort* __restrict__ W0F) {
    if (blockIdx.x >= NBLK2) {
        const int t = (blockIdx.x - NBLK2) * 128 + threadIdx.x;   // 0..4095
        const int lane = t & 63;
        const int grp = t >> 6;                                    // fi*8 + kc
        const int kc = grp & 7, fi = grp >> 3;
        const int n = fi * 16 + (lane & 15);
        const int k0 = kc * 32 + (lane >> 4) * 8;
        ushort v[8];
        #pragma unroll
        for (int j = 0; j < 8; ++j) v[j] = f2bf(W0[(k0 + j) * NHID + n]);
        uint4 u;
        u.x = (uint)v[0] | ((uint)v[1] << 16);
        u.y = (uint)v[2] | ((uint)v[3] << 16);
        u.z = (uint)v[4] | ((uint)v[5] << 16);
        u.w = (uint)v[6] | ((uint)v[7] << 16);
        *(uint4*)&W0F[(grp * 64 + lane) * 8] = u;
        return;
    }
    __shared__ uchar cnt8[128 * NBK];   // 25088 B, row t = thread-private
    const int t = threadIdx.x, blk = blockIdx.x;
    for (int i = t * 4; i < 128 * NBK; i += 512) *(uint*)&cnt8[i] = 0u;
    __syncthreads();
    const int base = blk * EPB2;
    #pragma unroll 4
    for (int k = 0; k < 32; ++k) {
        const int i = t + k * 128;
        if (i < EPB2) {
            const int b = ei[NEDGES + base + i] >> 8;
            ++cnt8[t * NBK + b];        // non-atomic, thread-private row
        }
    }
    __syncthreads();
    for (int c = t; c < NBK; c += 128) {
        int s = 0;
        for (int r = 0; r < 128; ++r) s += cnt8[r * NBK + c];
        bcnt[blk * NBK + c] = s;
    }
}

// ---------------- L2: scan -> bstart + per-(blk,bucket) dest offsets; zero stats ----------------
__global__ void k_bkscan(const int* __restrict__ bcnt, int* __restrict__ off,
                         int* __restrict__ bstart, int* __restrict__ rowptr,
                         float* __restrict__ stats) {
    __shared__ int sc[256];
    const int t = threadIdx.x;
    stats[t] = 0.f;
    int tot = 0;
    if (t < NBK)
        for (int b = 0; b < NBLK2; ++b) tot += bcnt[b * NBK + t];
    sc[t] = tot;
    __syncthreads();
    for (int o = 1; o < 256; o <<= 1) {
        const int v = (t >= o) ? sc[t - o] : 0;
        __syncthreads();
        sc[t] += v;
        __syncthreads();
    }
    const int excl = sc[t] - tot;
    if (t <= NBK) bstart[t] = excl;     // t==NBK -> total = NEDGES
    if (t == 0) rowptr[NNODES] = NEDGES;
    if (t < NBK) {
        int run = excl;
        for (int b = 0; b < NBLK2; ++b) { off[b * NBK + t] = run; run += bcnt[b * NBK + t]; }
    }
}

// ---------------- L3: atomic-free local sort + direct bucket-major write ----------------
__launch_bounds__(128)
__global__ void k_sortwrite(const int* __restrict__ ei, const int* __restrict__ off,
                            uint* __restrict__ packed2) {
    __shared__ uchar cnt8[128 * NBK];
    __shared__ int offl[NBK];
    const int t = threadIdx.x, blk = blockIdx.x;
    for (int i = t * 4; i < 128 * NBK; i += 512) *(uint*)&cnt8[i] = 0u;
    for (int c = t; c < NBK; c += 128) offl[c] = off[blk * NBK + c];
    __syncthreads();
    const int base = blk * EPB2;
    #pragma unroll 4
    for (int k = 0; k < 32; ++k) {
        const int i = t + k * 128;
        if (i < EPB2) {
            const int b = ei[NEDGES + base + i] >> 8;
            ++cnt8[t * NBK + b];
        }
    }
    __syncthreads();
    // column-wise exclusive prefix over threads (in place; totals <= ~45 fit u8)
    for (int c = t; c < NBK; c += 128) {
        int run = 0;
        for (int r = 0; r < 128; ++r) {
            const int v = cnt8[r * NBK + c];
            cnt8[r * NBK + c] = (uchar)run;
            run += v;
        }
    }
    __syncthreads();
    // replay in identical order; write directly to bucket-major position
    #pragma unroll 4
    for (int k = 0; k < 32; ++k) {
        const int i = t + k * 128;
        if (i < EPB2) {
            const int src = ei[base + i];
            const int dst = ei[NEDGES + base + i];
            const int b = dst >> 8;
            const int lp = cnt8[t * NBK + b];       // thread-private
            cnt8[t * NBK + b] = (uchar)(lp + 1);
            packed2[offl[b] + lp] = (uint)src | ((uint)(dst & 255) << 16);
        }
    }
}

// ---------------- L4: atomic-free per-bucket node sort -> esrc + rowptr ----------------
__launch_bounds__(128)
__global__ void k_bksort(const uint* __restrict__ packed2, const int* __restrict__ bstart,
                         int* __restrict__ esrc, int* __restrict__ rowptr) {
    __shared__ uchar cnt8[128 * 256];   // 32 KB, row t = thread-private
    __shared__ int nodebase[257];
    const int t = threadIdx.x, b = blockIdx.x;
    const int nb = bstart[b], ne = bstart[b + 1];
    const int n = ne - nb;
    {
        uint4* z = (uint4*)cnt8;
        const uint4 zz = make_uint4(0u, 0u, 0u, 0u);
        for (int i = t; i < 2048; i += 128) z[i] = zz;
    }
    __syncthreads();
    const int kmax = (n + 127) >> 7;
    for (int k = 0; k < kmax; ++k) {
        const int i = t + k * 128;
        if (i < n) {
            const uint p = packed2[nb + i];
            ++cnt8[t * 256 + (p >> 16)];
        }
    }
    __syncthreads();
    for (int c = t; c < 256; c += 128) {    // column prefix + totals
        int run = 0;
        for (int r = 0; r < 128; ++r) {
            const int v = cnt8[r * 256 + c];
            cnt8[r * 256 + c] = (uchar)run;
            run += v;
        }
        nodebase[c] = run;                  // column total (temp)
    }
    __syncthreads();
    if (t == 0) {
        int run = 0;
        for (int c = 0; c < 256; ++c) { const int v = nodebase[c]; nodebase[c] = run; run += v; }
        nodebase[256] = run;
    }
    __syncthreads();
    for (int c = t; c < 256; c += 128) {
        const int node = (b << 8) + c;
        if (node < NNODES) rowptr[node] = nb + nodebase[c];
    }
    for (int k = 0; k < kmax; ++k) {        // replay, same order
        const int i = t + k * 128;
        if (i < n) {
            const uint p = packed2[nb + i];
            const int nd = (int)(p >> 16);
            const int lp = cnt8[t * 256 + nd];
            cnt8[t * 256 + nd] = (uchar)(lp + 1);
            esrc[nb + nodebase[nd] + lp] = (int)(p & 0xFFFFu);
        }
    }
}

// ---------------- L5: GEMM1 (MFMA bf16, LDS-free, phased loads) ----------------
__launch_bounds__(256)
__global__ void k_gemm1(const float* __restrict__ x, const ushort* __restrict__ W0F,
                        uchar* __restrict__ h1) {
    const int gt = blockIdx.x * 256 + threadIdx.x;
    const int w = gt >> 6;
    if (w >= NW1) return;
    const int lane = gt & 63;
    const int half = w & 1;
    const int node = (w >> 1) * 16 + (lane & 15);
    const int nclamp = node < NNODES ? node : NNODES - 1;
    const float* xg = &x[(long)nclamp * NFEAT + (lane >> 4) * 8];

    float4 xa[8], xb[8];
    #pragma unroll
    for (int kc = 0; kc < 8; ++kc) {
        xa[kc] = *(const float4*)(xg + kc * 32);
        xb[kc] = *(const float4*)(xg + kc * 32 + 4);
    }
    __builtin_amdgcn_sched_barrier(0);
    bf16x8 xf[8];
    #pragma unroll
    for (int kc = 0; kc < 8; ++kc) {
        xf[kc][0]=(short)f2bf(xa[kc].x); xf[kc][1]=(short)f2bf(xa[kc].y);
        xf[kc][2]=(short)f2bf(xa[kc].z); xf[kc][3]=(short)f2bf(xa[kc].w);
        xf[kc][4]=(short)f2bf(xb[kc].x); xf[kc][5]=(short)f2bf(xb[kc].y);
        xf[kc][6]=(short)f2bf(xb[kc].z); xf[kc][7]=(short)f2bf(xb[kc].w);
    }
    __builtin_amdgcn_sched_barrier(0);
    f32x4 acc[4];
    #pragma unroll
    for (int f = 0; f < 4; ++f) acc[f] = (f32x4){0.f, 0.f, 0.f, 0.f};
    const ushort* wbase = &W0F[(size_t)lane * 8];
    #pragma unroll
    for (int kc = 0; kc < 8; ++kc) {
        #pragma unroll
        for (int f = 0; f < 4; ++f) {
            const int grp = (half * 4 + f) * 8 + kc;
            const bf16x8 wf = *(const bf16x8*)&wbase[(size_t)grp * 64 * 8];
            acc[f] = __builtin_amdgcn_mfma_f32_16x16x32_bf16(wf, xf[kc], acc[f], 0, 0, 0);
        }
    }
    if (node < NNODES) {
        const int nq = (lane >> 4) * 4;
        uchar* hp = &h1[(long)node * NHID + half * 64 + nq];
        #pragma unroll
        for (int f = 0; f < 4; ++f)
            *(uint*)&hp[f * 16] = pk_fp8x4(acc[f][0], acc[f][1], acc[f][2], acc[f][3]);
    }
}

// ---------------- L6: gather1: agg1[n] = b0 + sum h1[src] (fp8 in, f32 acc) ----------------
__launch_bounds__(256)
__global__ void k_gather1(const int* __restrict__ rowptr, const int* __restrict__ esrc,
                          const uchar* __restrict__ h1, const float* __restrict__ b0,
                          float* __restrict__ agg1) {
    const int w = (blockIdx.x * blockDim.x + threadIdx.x) >> 6;
    const int lane = threadIdx.x & 63;
    if (w >= NNODES) return;
    const int beg = rowptr[w], end = rowptr[w + 1];
    const int f = lane * 2;
    float2 acc = *(const float2*)&b0[f];
    int i = beg;
    for (; i + 7 < end; i += 8) {
        uint v[8];
        #pragma unroll
        for (int j = 0; j < 8; ++j)
            v[j] = (uint)*(const ushort*)&h1[(long)esrc[i + j] * NHID + f];
        #pragma unroll
        for (int j = 0; j < 8; ++j) { acc.x += fp8lo(v[j]); acc.y += fp8hi(v[j]); }
    }
    for (; i < end; ++i) {
        const uint v = (uint)*(const ushort*)&h1[(long)esrc[i] * NHID + f];
        acc.x += fp8lo(v); acc.y += fp8hi(v);
    }
    *(float2*)&agg1[(long)w * NHID + f] = acc;
}

// ---------------- L7: BN stats (float4) ----------------
__global__ void k_bnstats(const float* __restrict__ agg1,
                          float* __restrict__ sums, float* __restrict__ sumsq) {
    __shared__ float sd[256 * 4], sd2[256 * 4];
    const int t = threadIdx.x;
    const int c4 = (t & 31) * 4;
    const int rr = t >> 5;
    float4 s = make_float4(0.f,0.f,0.f,0.f), s2 = s;
    for (int r = blockIdx.x * 8 + rr; r < NNODES; r += gridDim.x * 8) {
        const float4 v = *(const float4*)&agg1[(long)r * NHID + c4];
        s.x += v.x; s.y += v.y; s.z += v.z; s.w += v.w;
        s2.x += v.x*v.x; s2.y += v.y*v.y; s2.z += v.z*v.z; s2.w += v.w*v.w;
    }
    *(float4*)&sd[t * 4] = s; *(float4*)&sd2[t * 4] = s2;
    __syncthreads();
    if (t < 32) {
        #pragma unroll
        for (int j = 1; j < 8; ++j) {
            const float4 a = *(const float4*)&sd[(j * 32 + t) * 4];
            const float4 a2 = *(const float4*)&sd2[(j * 32 + t) * 4];
            s = *(float4*)&sd[t * 4];
            s2 = *(float4*)&sd2[t * 4];
            s.x += a.x; s.y += a.y; s.z += a.z; s.w += a.w;
            s2.x += a2.x; s2.y += a2.y; s2.z += a2.z; s2.w += a2.w;
            *(float4*)&sd[t * 4] = s; *(float4*)&sd2[t * 4] = s2;
        }
        atomicAdd(&sums[c4 + 0], s.x);  atomicAdd(&sums[c4 + 1], s.y);
        atomicAdd(&sums[c4 + 2], s.z);  atomicAdd(&sums[c4 + 3], s.w);
        atomicAdd(&sumsq[c4 + 0], s2.x); atomicAdd(&sumsq[c4 + 1], s2.y);
        atomicAdd(&sumsq[c4 + 2], s2.z); atomicAdd(&sumsq[c4 + 3], s2.w);
    }
}

// ---------------- L8: GEMM2 with inlined BN-final + ReLU ----------------
__launch_bounds__(256)
__global__ void k_gemm2(const float* __restrict__ agg1, const float* __restrict__ W1,
                        const float* __restrict__ sums, const float* __restrict__ sumsq,
                        const float* __restrict__ gamma, const float* __restrict__ beta,
                        ushort* __restrict__ h2) {
    __shared__ float xs[64 * 132];
    __shared__ float wt[40 * 132];
    __shared__ float s_scale[128], s_shift[128];
    const int t = threadIdx.x;
    const int base = blockIdx.x * 64;

    if (t < NHID) {
        const float mu = sums[t] * (1.f / NNODES);
        float var = sumsq[t] * (1.f / NNODES) - mu * mu;
        var = fmaxf(var, 0.f);
        const float sc = gamma[t] * rsqrtf(var + BN_EPS);
        s_scale[t] = sc;
        s_shift[t] = beta[t] - mu * sc;
    }
    for (int idx = t; idx < NHID * NCLASS; idx += 256) {
        const int c = idx / NCLASS, j = idx % NCLASS;
        wt[j * 132 + c] = W1[idx];
    }
    __syncthreads();
    {
        const int cc = (t & 31) * 4;
        const float4 sc = *(const float4*)&s_scale[cc];
        const float4 sh = *(const float4*)&s_shift[cc];
        const int rb = t >> 5;
        #pragma unroll
        for (int p = 0; p < 8; ++p) {
            const int row = p * 8 + rb;
            const int g = base + row;
            float4 v = make_float4(0.f, 0.f, 0.f, 0.f);
            if (g < NNODES) {
                const float4 a = *(const float4*)&agg1[(long)g * NHID + cc];
                v.x = fmaxf(a.x * sc.x + sh.x, 0.f);
                v.y = fmaxf(a.y * sc.y + sh.y, 0.f);
                v.z = fmaxf(a.z * sc.z + sh.z, 0.f);
                v.w = fmaxf(a.w * sc.w + sh.w, 0.f);
            }
            *(float4*)&xs[row * 132 + cc] = v;
        }
    }
    __syncthreads();

    const int node = t >> 2;
    const int j0 = (t & 3) * 10;
    float acc[10] = {};
    for (int c4 = 0; c4 < 32; ++c4) {
        const int c = c4 * 4;
        const float4 a = *(const float4*)&xs[node * 132 + c];
        #pragma unroll
        for (int jj = 0; jj < 10; ++jj) {
            const float4 wv = *(const float4*)&wt[(j0 + jj) * 132 + c];
            acc[jj] += a.x * wv.x + a.y * wv.y + a.z * wv.z + a.w * wv.w;
        }
    }
    const int g = base + node;
    if (g < NNODES) {
        #pragma unroll
        for (int p = 0; p < 5; ++p) {
            uint u = (uint)f2bf(acc[2 * p]) | ((uint)f2bf(acc[2 * p + 1]) << 16);
            *(uint*)&h2[(long)g * NCLASS + j0 + 2 * p] = u;
        }
    }
}

// ---------------- L9: gather2: out[n] = b1 + sum h2[src] (12 nodes/block) ----------------
__launch_bounds__(256)
__global__ void k_gather2(const int* __restrict__ rowptr, const int* __restrict__ esrc,
                          const ushort* __restrict__ h2, const float* __restrict__ b1,
                          float* __restrict__ out) {
    const int t = threadIdx.x;
    if (t >= 240) return;
    const int node = blockIdx.x * 12 + t / 20;
    if (node >= NNODES) return;
    const int f = (t % 20) * 2;
    const int beg = rowptr[node], end = rowptr[node + 1];
    float2 acc = make_float2(b1[f], b1[f + 1]);
    int i = beg;
    for (; i + 3 < end; i += 4) {
        const uint v0 = *(const uint*)&h2[(long)esrc[i]     * NCLASS + f];
        const uint v1 = *(const uint*)&h2[(long)esrc[i + 1] * NCLASS + f];
        const uint v2 = *(const uint*)&h2[(long)esrc[i + 2] * NCLASS + f];
        const uint v3 = *(const uint*)&h2[(long)esrc[i + 3] * NCLASS + f];
        acc.x += (bflo(v0) + bflo(v1)) + (bflo(v2) + bflo(v3));
        acc.y += (bfhi(v0) + bfhi(v1)) + (bfhi(v2) + bfhi(v3));
    }
    for (; i < end; ++i) {
        const uint v = *(const uint*)&h2[(long)esrc[i] * NCLASS + f];
        acc.x += bflo(v); acc.y += bfhi(v);
    }
    *(float2*)&out[(long)node * NCLASS + f] = acc;
}

extern "C" void kernel_launch(void* const* d_in, const int* in_sizes, int n_in,
                              void* d_out, int out_size, void* d_ws, size_t ws_size,
                              hipStream_t stream) {
    const float* x      = (const float*)d_in[0];
    const int*   ei     = (const int*)d_in[1];
    const float* W0     = (const float*)d_in[2];
    const float* b0     = (const float*)d_in[3];
    const float* gamma0 = (const float*)d_in[4];
    const float* beta0  = (const float*)d_in[5];
    const float* W1     = (const float*)d_in[6];
    const float* b1     = (const float*)d_in[7];
    float* out = (float*)d_out;

    char* ws = (char*)d_ws;
    float* sums  = (float*)ws;                 // 128
    float* sumsq = sums + 128;                 // 128
    int* wsI     = (int*)(ws + 4096);
    int* rowptr  = wsI;                        // 50001 (pad 50048)
    int* esrc    = wsI + 50048;                // 800000 -> 850048
    int* bcnt    = wsI + 850048;               // 39200 (pad 39296) -> 889344
    int* off     = wsI + 889344;               // 39200 (pad 39296) -> 928640
    int* bstart  = wsI + 928640;               // 197 (pad 384)
    ushort* W0F  = (ushort*)(ws + 3720192);    // 64 KB fragment-major
    uchar* h1    = (uchar*)(ws + 3785728);     // 50000*128 fp8 = 6.4 MB
    float* agg1  = (float*)(ws + 16429056);    // 50000*128 f32 = 25.6 MB
    uint* packed2 = (uint*)agg1;               // 3.2 MB, dead before gather1
    ushort* h2   = (ushort*)h1;                // 4 MB, h1 region dead after gather1

    k_count<<<NBLK2 + 32, 128, 0, stream>>>(ei, bcnt, W0, W0F);
    k_bkscan<<<1, 256, 0, stream>>>(bcnt, off, bstart, rowptr, sums);
    k_sortwrite<<<NBLK2, 128, 0, stream>>>(ei, off, packed2);
    k_bksort<<<NBK, 128, 0, stream>>>(packed2, bstart, esrc, rowptr);
    k_gemm1<<<GEMM1_BLOCKS, 256, 0, stream>>>(x, W0F, h1);
    k_gather1<<<(NNODES * 64 + 255) / 256, 256, 0, stream>>>(rowptr, esrc, h1, b0, agg1);
    k_bnstats<<<256, 256, 0, stream>>>(agg1, sums, sumsq);
    k_gemm2<<<(NNODES + 63) / 64, 256, 0, stream>>>(agg1, W1, sums, sumsq, gamma0, beta0, h2);
    k_gather2<<<(NNODES + 11) / 12, 256, 0, stream>>>(rowptr, esrc, h2, b1, out);
}

// Round 12
// 169.158 us; speedup vs baseline: 1.2525x; 1.2525x over previous
//
#include <hip/hip_runtime.h>
#include <hip/hip_fp8.h>

#define NFEAT 256
#define NHID 128
#define NCLASS 40
#define NNODES 50000
#define NEDGES 800000
#define BN_EPS 1e-5f
#define NBK 196          // buckets = dst>>8  (256 nodes each)
#define NBLK 100         // edge blocks of 8000
#define EPB 8000
#define BKCAP 6144       // per-bucket LDS capacity (avg 4082, sigma 64)
#define NW1 6250         // gemm1 waves: 3125 node-groups x 2 hid-halves
#define GEMM1_BLOCKS 1563

typedef __attribute__((ext_vector_type(4))) float f32x4;
typedef __attribute__((ext_vector_type(8))) short bf16x8;

__device__ inline ushort f2bf(float f) {          // RNE f32 -> bf16
    uint u = __float_as_uint(f);
    u += 0x7FFF + ((u >> 16) & 1);
    return (ushort)(u >> 16);
}
__device__ inline float bflo(uint v) { return __uint_as_float(v << 16); }
__device__ inline float bfhi(uint v) { return __uint_as_float(v & 0xFFFF0000u); }

// fp8 e4m3 pack/unpack (HW cvt on gfx950; HIP-type fallback)
__device__ inline uint pk_fp8x4(float a0, float a1, float a2, float a3) {
#if __has_builtin(__builtin_amdgcn_cvt_pk_fp8_f32)
    int u = 0;
    u = __builtin_amdgcn_cvt_pk_fp8_f32(a0, a1, u, false);
    u = __builtin_amdgcn_cvt_pk_fp8_f32(a2, a3, u, true);
    return (uint)u;
#else
    __hip_fp8_e4m3 q0(a0), q1(a1), q2(a2), q3(a3);
    return (uint)q0.__x | ((uint)q1.__x << 8) | ((uint)q2.__x << 16) | ((uint)q3.__x << 24);
#endif
}
__device__ inline float fp8lo(uint v) {
#if __has_builtin(__builtin_amdgcn_cvt_f32_fp8)
    return __builtin_amdgcn_cvt_f32_fp8((int)v, 0);
#else
    __hip_fp8_e4m3 q; q.__x = (__hip_fp8_storage_t)(v & 0xFF); return (float)q;
#endif
}
__device__ inline float fp8hi(uint v) {
#if __has_builtin(__builtin_amdgcn_cvt_f32_fp8)
    return __builtin_amdgcn_cvt_f32_fp8((int)v, 1);
#else
    __hip_fp8_e4m3 q; q.__x = (__hip_fp8_storage_t)((v >> 8) & 0xFF); return (float)q;
#endif
}

// ---------------- L1: W0 repack (blocks 0-15) + bucket count (blocks 16-115) ----------------
__global__ void k_prep(const float* __restrict__ W0, ushort* __restrict__ W0F,
                       const int* __restrict__ ei, int* __restrict__ bcnt) {
    __shared__ int cnt[NBK];
    if (blockIdx.x < 16) {
        const int t = blockIdx.x * 256 + threadIdx.x;   // 0..4095
        const int lane = t & 63;
        const int grp = t >> 6;                          // fi*8 + kc
        const int kc = grp & 7, fi = grp >> 3;
        const int n = fi * 16 + (lane & 15);
        const int k0 = kc * 32 + (lane >> 4) * 8;
        ushort v[8];
        #pragma unroll
        for (int j = 0; j < 8; ++j) v[j] = f2bf(W0[(k0 + j) * NHID + n]);
        uint4 u;
        u.x = (uint)v[0] | ((uint)v[1] << 16);
        u.y = (uint)v[2] | ((uint)v[3] << 16);
        u.z = (uint)v[4] | ((uint)v[5] << 16);
        u.w = (uint)v[6] | ((uint)v[7] << 16);
        *(uint4*)&W0F[(grp * 64 + lane) * 8] = u;
    } else {
        const int blk = blockIdx.x - 16;
        const int t = threadIdx.x;
        if (t < NBK) cnt[t] = 0;
        __syncthreads();
        const int base = blk * EPB;
        for (int i = t; i < EPB; i += 256)
            atomicAdd(&cnt[ei[NEDGES + base + i] >> 8], 1);
        __syncthreads();
        if (t < NBK) bcnt[blk * NBK + t] = cnt[t];
    }
}

// ---------------- L2: parallel scan -> bstart + per-block offsets; zero stats ----------------
__global__ void k_bkscan(const int* __restrict__ bcnt, int* __restrict__ off,
                         int* __restrict__ bstart, int* __restrict__ rowptr,
                         float* __restrict__ stats) {
    __shared__ int sc[256];
    const int t = threadIdx.x;
    stats[t] = 0.f;
    int tot = 0;
    if (t < NBK)
        for (int b = 0; b < NBLK; ++b) tot += bcnt[b * NBK + t];
    sc[t] = tot;
    __syncthreads();
    for (int o = 1; o < 256; o <<= 1) {
        const int v = (t >= o) ? sc[t - o] : 0;
        __syncthreads();
        sc[t] += v;
        __syncthreads();
    }
    const int excl = sc[t] - tot;
    if (t < NBK) bstart[t] = excl;
    else if (t == NBK) bstart[NBK] = sc[NBK - 1];
    if (t == 0) rowptr[NNODES] = NEDGES;
    if (t < NBK) {
        int run = excl;
        for (int b = 0; b < NBLK; ++b) { off[b * NBK + t] = run; run += bcnt[b * NBK + t]; }
    }
}

// ---------------- L3: bucket scatter (blocks 0-99) + GEMM1 (blocks 100+) ----------------
// __launch_bounds__(256, 1): let regalloc keep all 16 x-loads + W0F frags in flight.
__launch_bounds__(256, 1)
__global__ void k_scatter_gemm1(const int* __restrict__ ei, const int* __restrict__ off,
                                uint* __restrict__ packed,
                                const float* __restrict__ x, const ushort* __restrict__ W0F,
                                uchar* __restrict__ h1) {
    __shared__ int cur[NBK];
    if (blockIdx.x < NBLK) {
        const int t = threadIdx.x, blk = blockIdx.x;
        if (t < NBK) cur[t] = off[blk * NBK + t];
        __syncthreads();
        const int base = blk * EPB;
        for (int i = t; i < EPB; i += 256) {
            const int src = ei[base + i];
            const int dst = ei[NEDGES + base + i];
            const int pos = atomicAdd(&cur[dst >> 8], 1);
            packed[pos] = (uint)src | ((uint)(dst & 255) << 16);
        }
    } else {
        const int gt = (blockIdx.x - NBLK) * 256 + threadIdx.x;
        const int w = gt >> 6;
        if (w >= NW1) return;
        const int lane = gt & 63;
        const int half = w & 1;
        const int node = (w >> 1) * 16 + (lane & 15);
        const int nclamp = node < NNODES ? node : NNODES - 1;
        const float* xg = &x[(long)nclamp * NFEAT + (lane >> 4) * 8];

        // phase 1: ALL 16 loads in flight
        float4 xa[8], xb[8];
        #pragma unroll
        for (int kc = 0; kc < 8; ++kc) {
            xa[kc] = *(const float4*)(xg + kc * 32);
            xb[kc] = *(const float4*)(xg + kc * 32 + 4);
        }
        __builtin_amdgcn_sched_barrier(0);
        // phase 2: convert
        bf16x8 xf[8];
        #pragma unroll
        for (int kc = 0; kc < 8; ++kc) {
            xf[kc][0]=(short)f2bf(xa[kc].x); xf[kc][1]=(short)f2bf(xa[kc].y);
            xf[kc][2]=(short)f2bf(xa[kc].z); xf[kc][3]=(short)f2bf(xa[kc].w);
            xf[kc][4]=(short)f2bf(xb[kc].x); xf[kc][5]=(short)f2bf(xb[kc].y);
            xf[kc][6]=(short)f2bf(xb[kc].z); xf[kc][7]=(short)f2bf(xb[kc].w);
        }
        __builtin_amdgcn_sched_barrier(0);
        // phase 3: MFMA over W0F (L2-hot, coalesced fragment loads)
        f32x4 acc[4];
        #pragma unroll
        for (int f = 0; f < 4; ++f) acc[f] = (f32x4){0.f, 0.f, 0.f, 0.f};
        const ushort* wbase = &W0F[(size_t)lane * 8];
        #pragma unroll
        for (int kc = 0; kc < 8; ++kc) {
            #pragma unroll
            for (int f = 0; f < 4; ++f) {
                const int grp = (half * 4 + f) * 8 + kc;
                const bf16x8 wf = *(const bf16x8*)&wbase[(size_t)grp * 64 * 8];
                acc[f] = __builtin_amdgcn_mfma_f32_16x16x32_bf16(wf, xf[kc], acc[f], 0, 0, 0);
            }
        }
        // epilogue: fp8 pack, 4 hid per fragment
        if (node < NNODES) {
            const int nq = (lane >> 4) * 4;
            uchar* hp = &h1[(long)node * NHID + half * 64 + nq];
            #pragma unroll
            for (int f = 0; f < 4; ++f)
                *(uint*)&hp[f * 16] = pk_fp8x4(acc[f][0], acc[f][1], acc[f][2], acc[f][3]);
        }
    }
}

// ---------------- L4: per-bucket LDS counting sort -> esrc + rowptr ----------------
__launch_bounds__(256)
__global__ void k_bksort(const uint* __restrict__ packed, const int* __restrict__ bstart,
                         int* __restrict__ esrc, int* __restrict__ rowptr) {
    __shared__ uint pr[BKCAP];
    __shared__ int cnt[256], sc[256], cur[256];
    const int t = threadIdx.x, b = blockIdx.x;
    const int nb = bstart[b], ne = bstart[b + 1];
    const int n = ne - nb;
    cnt[t] = 0;
    __syncthreads();
    for (int i = t; i < n; i += 256) {
        const uint p = packed[nb + i];
        pr[i] = p;
        atomicAdd(&cnt[p >> 16], 1);
    }
    __syncthreads();
    const int v = cnt[t];
    sc[t] = v;
    __syncthreads();
    for (int o = 1; o < 256; o <<= 1) {
        const int tmp = (t >= o) ? sc[t - o] : 0;
        __syncthreads();
        sc[t] += tmp;
        __syncthreads();
    }
    const int excl = sc[t] - v;
    cur[t] = excl;
    const int node = (b << 8) + t;
    if (node < NNODES) rowptr[node] = nb + excl;
    __syncthreads();
    for (int i = t; i < n; i += 256) {
        const uint p = pr[i];
        const int pos = atomicAdd(&cur[p >> 16], 1);
        esrc[nb + pos] = (int)(p & 0xFFFFu);
    }
}

// ---------------- L5: gather1: agg1[n] = b0 + sum h1[src] (fp8 in, f32 acc) ----------------
__launch_bounds__(256)
__global__ void k_gather1(const int* __restrict__ rowptr, const int* __restrict__ esrc,
                          const uchar* __restrict__ h1, const float* __restrict__ b0,
                          float* __restrict__ agg1) {
    const int w = (blockIdx.x * blockDim.x + threadIdx.x) >> 6;
    const int lane = threadIdx.x & 63;
    if (w >= NNODES) return;
    const int beg = rowptr[w], end = rowptr[w + 1];
    const int f = lane * 2;
    float2 acc = *(const float2*)&b0[f];
    int i = beg;
    for (; i + 7 < end; i += 8) {
        uint v[8];
        #pragma unroll
        for (int j = 0; j < 8; ++j)
            v[j] = (uint)*(const ushort*)&h1[(long)esrc[i + j] * NHID + f];
        #pragma unroll
        for (int j = 0; j < 8; ++j) { acc.x += fp8lo(v[j]); acc.y += fp8hi(v[j]); }
    }
    for (; i < end; ++i) {
        const uint v = (uint)*(const ushort*)&h1[(long)esrc[i] * NHID + f];
        acc.x += fp8lo(v); acc.y += fp8hi(v);
    }
    *(float2*)&agg1[(long)w * NHID + f] = acc;
}

// ---------------- L6: BN stats (float4) ----------------
__global__ void k_bnstats(const float* __restrict__ agg1,
                          float* __restrict__ sums, float* __restrict__ sumsq) {
    __shared__ float sd[256 * 4], sd2[256 * 4];
    const int t = threadIdx.x;
    const int c4 = (t & 31) * 4;
    const int rr = t >> 5;
    float4 s = make_float4(0.f,0.f,0.f,0.f), s2 = s;
    for (int r = blockIdx.x * 8 + rr; r < NNODES; r += gridDim.x * 8) {
        const float4 v = *(const float4*)&agg1[(long)r * NHID + c4];
        s.x += v.x; s.y += v.y; s.z += v.z; s.w += v.w;
        s2.x += v.x*v.x; s2.y += v.y*v.y; s2.z += v.z*v.z; s2.w += v.w*v.w;
    }
    *(float4*)&sd[t * 4] = s; *(float4*)&sd2[t * 4] = s2;
    __syncthreads();
    if (t < 32) {
        #pragma unroll
        for (int j = 1; j < 8; ++j) {
            const float4 a = *(const float4*)&sd[(j * 32 + t) * 4];
            const float4 a2 = *(const float4*)&sd2[(j * 32 + t) * 4];
            s = *(float4*)&sd[t * 4];
            s2 = *(float4*)&sd2[t * 4];
            s.x += a.x; s.y += a.y; s.z += a.z; s.w += a.w;
            s2.x += a2.x; s2.y += a2.y; s2.z += a2.z; s2.w += a2.w;
            *(float4*)&sd[t * 4] = s; *(float4*)&sd2[t * 4] = s2;
        }
        atomicAdd(&sums[c4 + 0], s.x);  atomicAdd(&sums[c4 + 1], s.y);
        atomicAdd(&sums[c4 + 2], s.z);  atomicAdd(&sums[c4 + 3], s.w);
        atomicAdd(&sumsq[c4 + 0], s2.x); atomicAdd(&sumsq[c4 + 1], s2.y);
        atomicAdd(&sumsq[c4 + 2], s2.z); atomicAdd(&sumsq[c4 + 3], s2.w);
    }
}

// ---------------- L7: GEMM2 with inlined BN-final + ReLU ----------------
__launch_bounds__(256)
__global__ void k_gemm2(const float* __restrict__ agg1, const float* __restrict__ W1,
                        const float* __restrict__ sums, const float* __restrict__ sumsq,
                        const float* __restrict__ gamma, const float* __restrict__ beta,
                        ushort* __restrict__ h2) {
    __shared__ float xs[64 * 132];
    __shared__ float wt[40 * 132];
    __shared__ float s_scale[128], s_shift[128];
    const int t = threadIdx.x;
    const int base = blockIdx.x * 64;

    if (t < NHID) {
        const float mu = sums[t] * (1.f / NNODES);
        float var = sumsq[t] * (1.f / NNODES) - mu * mu;
        var = fmaxf(var, 0.f);
        const float sc = gamma[t] * rsqrtf(var + BN_EPS);
        s_scale[t] = sc;
        s_shift[t] = beta[t] - mu * sc;
    }
    for (int idx = t; idx < NHID * NCLASS; idx += 256) {
        const int c = idx / NCLASS, j = idx % NCLASS;
        wt[j * 132 + c] = W1[idx];
    }
    __syncthreads();
    {
        const int cc = (t & 31) * 4;
        const float4 sc = *(const float4*)&s_scale[cc];
        const float4 sh = *(const float4*)&s_shift[cc];
        const int rb = t >> 5;
        #pragma unroll
        for (int p = 0; p < 8; ++p) {
            const int row = p * 8 + rb;
            const int g = base + row;
            float4 v = make_float4(0.f, 0.f, 0.f, 0.f);
            if (g < NNODES) {
                const float4 a = *(const float4*)&agg1[(long)g * NHID + cc];
                v.x = fmaxf(a.x * sc.x + sh.x, 0.f);
                v.y = fmaxf(a.y * sc.y + sh.y, 0.f);
                v.z = fmaxf(a.z * sc.z + sh.z, 0.f);
                v.w = fmaxf(a.w * sc.w + sh.w, 0.f);
            }
            *(float4*)&xs[row * 132 + cc] = v;
        }
    }
    __syncthreads();

    const int node = t >> 2;
    const int j0 = (t & 3) * 10;
    float acc[10] = {};
    for (int c4 = 0; c4 < 32; ++c4) {
        const int c = c4 * 4;
        const float4 a = *(const float4*)&xs[node * 132 + c];
        #pragma unroll
        for (int jj = 0; jj < 10; ++jj) {
            const float4 wv = *(const float4*)&wt[(j0 + jj) * 132 + c];
            acc[jj] += a.x * wv.x + a.y * wv.y + a.z * wv.z + a.w * wv.w;
        }
    }
    const int g = base + node;
    if (g < NNODES) {
        #pragma unroll
        for (int p = 0; p < 5; ++p) {
            uint u = (uint)f2bf(acc[2 * p]) | ((uint)f2bf(acc[2 * p + 1]) << 16);
            *(uint*)&h2[(long)g * NCLASS + j0 + 2 * p] = u;
        }
    }
}

// ---------------- L8: gather2: out[n] = b1 + sum h2[src] (12 nodes/block) ----------------
__launch_bounds__(256)
__global__ void k_gather2(const int* __restrict__ rowptr, const int* __restrict__ esrc,
                          const ushort* __restrict__ h2, const float* __restrict__ b1,
                          float* __restrict__ out) {
    const int t = threadIdx.x;
    if (t >= 240) return;
    const int node = blockIdx.x * 12 + t / 20;
    if (node >= NNODES) return;
    const int f = (t % 20) * 2;
    const int beg = rowptr[node], end = rowptr[node + 1];
    float2 acc = make_float2(b1[f], b1[f + 1]);
    int i = beg;
    for (; i + 3 < end; i += 4) {
        const uint v0 = *(const uint*)&h2[(long)esrc[i]     * NCLASS + f];
        const uint v1 = *(const uint*)&h2[(long)esrc[i + 1] * NCLASS + f];
        const uint v2 = *(const uint*)&h2[(long)esrc[i + 2] * NCLASS + f];
        const uint v3 = *(const uint*)&h2[(long)esrc[i + 3] * NCLASS + f];
        acc.x += (bflo(v0) + bflo(v1)) + (bflo(v2) + bflo(v3));
        acc.y += (bfhi(v0) + bfhi(v1)) + (bfhi(v2) + bfhi(v3));
    }
    for (; i < end; ++i) {
        const uint v = *(const uint*)&h2[(long)esrc[i] * NCLASS + f];
        acc.x += bflo(v); acc.y += bfhi(v);
    }
    *(float2*)&out[(long)node * NCLASS + f] = acc;
}

extern "C" void kernel_launch(void* const* d_in, const int* in_sizes, int n_in,
                              void* d_out, int out_size, void* d_ws, size_t ws_size,
                              hipStream_t stream) {
    const float* x      = (const float*)d_in[0];
    const int*   ei     = (const int*)d_in[1];
    const float* W0     = (const float*)d_in[2];
    const float* b0     = (const float*)d_in[3];
    const float* gamma0 = (const float*)d_in[4];
    const float* beta0  = (const float*)d_in[5];
    const float* W1     = (const float*)d_in[6];
    const float* b1     = (const float*)d_in[7];
    float* out = (float*)d_out;

    char* ws = (char*)d_ws;
    float* sums  = (float*)ws;                 // 128
    float* sumsq = sums + 128;                 // 128
    int* wsI     = (int*)(ws + 4096);
    int* rowptr  = wsI;                        // 50001 (pad 50048)
    int* esrc    = wsI + 50048;                // 800000
    int* bcnt    = wsI + 850048;               // 19600 (pad 19648)
    int* off     = wsI + 869696;               // 19600 (pad 19648)
    int* bstart  = wsI + 889344;               // 197 (pad 256)
    ushort* W0F  = (ushort*)(ws + 3563520);    // 64 KB fragment-major
    uchar* h1    = (uchar*)(ws + 3629056);     // 50000*128 fp8 = 6.4 MB
    float* agg1  = (float*)(ws + 16429056);    // 50000*128 f32 = 25.6 MB
    uint* packed = (uint*)agg1;                // 3.2 MB, dead before gather1
    ushort* h2   = (ushort*)h1;                // 4 MB, h1 region dead after gather1

    k_prep<<<16 + NBLK, 256, 0, stream>>>(W0, W0F, ei, bcnt);
    k_bkscan<<<1, 256, 0, stream>>>(bcnt, off, bstart, rowptr, sums);
    k_scatter_gemm1<<<NBLK + GEMM1_BLOCKS, 256, 0, stream>>>(ei, off, packed, x, W0F, h1);
    k_bksort<<<NBK, 256, 0, stream>>>(packed, bstart, esrc, rowptr);
    k_gather1<<<(NNODES * 64 + 255) / 256, 256, 0, stream>>>(rowptr, esrc, h1, b0, agg1);
    k_bnstats<<<256, 256, 0, stream>>>(agg1, sums, sumsq);
    k_gemm2<<<(NNODES + 63) / 64, 256, 0, stream>>>(agg1, W1, sums, sumsq, gamma0, beta0, h2);
    k_gather2<<<(NNODES + 11) / 12, 256, 0, stream>>>(rowptr, esrc, h2, b1, out);
}